// Round 12
// baseline (1084.937 us; speedup 1.0000x reference)
//
#include <hip/hip_runtime.h>
#include <hip/hip_bf16.h>
#include <stdint.h>

#define BATCH 64
#define SEQ   2048
#define HID   1024
#define EDIM  2048   // 2*HID

#define BM 64         // rows per block
#define BN 512        // cols per block (n-split = 2)
#define BK 32
#define KSTEPS (EDIM / BK)   // 64
#define BS (BATCH * SEQ)

typedef __bf16 bf16x8 __attribute__((ext_vector_type(8)));
typedef float  f32x16 __attribute__((ext_vector_type(16)));
typedef float  f32x4a __attribute__((ext_vector_type(4)));

__device__ __forceinline__ unsigned short f2bf(float x) {
    __hip_bfloat16 h = __float2bfloat16(x);
    return __builtin_bit_cast(unsigned short, h);
}

__device__ __forceinline__ uint4 pack8(f32x4a f0, f32x4a f1) {
    uint4 r;
    r.x = (unsigned)f2bf(f0.x) | ((unsigned)f2bf(f0.y) << 16);
    r.y = (unsigned)f2bf(f0.z) | ((unsigned)f2bf(f0.w) << 16);
    r.z = (unsigned)f2bf(f1.x) | ((unsigned)f2bf(f1.y) << 16);
    r.w = (unsigned)f2bf(f1.z) | ((unsigned)f2bf(f1.w) << 16);
    return r;
}

__device__ __forceinline__ f32x4a ntload4(const float* p) {
    return __builtin_nontemporal_load((const f32x4a*)p);
}

// A-tile LDS byte addr: 64 rows x 64B, granule slot XOR-swizzled
__device__ __forceinline__ int a_addr(int row, int g) {
    int slot = g ^ ((row & 3) ^ ((row >> 2) & 3));
    return (row << 6) + (slot << 4);
}

// ---------------- prep: W_h (EDIM x HID fp32) -> Wt bf16 granule-major:
// element (h,e) at Wt[(e>>3)*8192 + h*8 + (e&7)]  (fragment = contiguous 16B)
__global__ void wh_transpose_kernel(const float* __restrict__ Wh,
                                    unsigned short* __restrict__ Wt) {
    __shared__ float tile[32][33];
    int bx = blockIdx.x & 63;    // e-tile
    int by = blockIdx.x >> 6;    // h-tile
    int e0 = bx * 32, h0 = by * 32;
    int tx = threadIdx.x & 31, ty = threadIdx.x >> 5;   // 32 x 8
    #pragma unroll
    for (int i = 0; i < 4; ++i)
        tile[ty + 8 * i][tx] = Wh[(size_t)(e0 + ty + 8 * i) * HID + h0 + tx];
    __syncthreads();
    if (ty < 4) {
        uint4 wv;
        unsigned short* ws = (unsigned short*)&wv;
        #pragma unroll
        for (int j = 0; j < 8; ++j) ws[j] = f2bf(tile[ty * 8 + j][tx]);
        *(uint4*)&Wt[(size_t)((e0 >> 3) + ty) * 8192 + (size_t)(h0 + tx) * 8] = wv;
    }
}

// ---------------- prep: dec_proj = decoder_hidden @ W_d  (fp32, (B,HID))
__global__ void dec_proj_kernel(const float* __restrict__ dec,
                                const float* __restrict__ Wd,
                                float* __restrict__ dp) {
    int gid = blockIdx.x * 256 + threadIdx.x;
    int b = gid >> 10, h = gid & 1023;
    const float* dr = dec + b * HID;
    float acc = 0.f;
    #pragma unroll 4
    for (int k = 0; k < HID; ++k) acc = fmaf(dr[k], Wd[(size_t)k * HID + h], acc);
    dp[gid] = acc;
}

#define MFMA32(a, bfv, c) __builtin_amdgcn_mfma_f32_32x32x16_bf16(a, bfv, c, 0, 0, 0)

// ---------------- main fused scores kernel: 64 rows x 512 cols, 8 waves,
// 32x32x16 MFMA (2495 TF rate), wave-tile 64x64, B global->reg from L2-resident
// Wt, A via tiny LDS dbuf. 2 blocks/CU (acc 64 AGPR, ~120 VGPR total).
__global__ __launch_bounds__(512, 4) void scores_kernel(
    const float* __restrict__ enc, const float* __restrict__ cov,
    const unsigned short* __restrict__ Wt, const float* __restrict__ dp,
    const float* __restrict__ Wc, const float* __restrict__ vv,
    float* __restrict__ spart_out)
{
    __shared__ char Al[2][4096];       // A dbuf: 64 rows x 64B, swizzled
    __shared__ float cov_s[BM];
    __shared__ float sred[BM][8];

    const int tid  = threadIdx.x;
    const int lane = tid & 63;
    const int wid  = tid >> 6;       // 0..7 : 64-col slice
    const int l31  = lane & 31;
    const int g2   = lane >> 5;      // 0..1 : k-granule within k-sub

    // bid pairs: (m, half=0/1) adjacent -> enc panel L3-hot on 2nd read
    const int bid  = blockIdx.x;
    const int half = bid & 1;
    const int m    = bid >> 1;                 // 0..2047
    const int b    = m >> 5;
    const int s0   = (m & 31) * BM;

    const float* Abase = enc + (size_t)(b * SEQ + s0) * EDIM;
    // A staging: threads 0..255, one (row, granule) 16B pack each
    const int arow = tid >> 2;                 // 0..63
    const int ag   = tid & 3;

    // per-lane B base: granule g2, col h = half*512 + wid*64 + l31
    const unsigned short* bptr =
        Wt + (size_t)g2 * 8192 + (size_t)(half * BN + wid * 64 + l31) * 8;

    f32x16 acc[2][2];
    #pragma unroll
    for (int mi = 0; mi < 2; ++mi)
        #pragma unroll
        for (int nj = 0; nj < 2; ++nj)
            #pragma unroll
            for (int r = 0; r < 16; ++r) acc[mi][nj][r] = 0.f;

    if (tid < BM) cov_s[tid] = cov[b * SEQ + s0 + tid];

    // prologue: stage A(0) into buffer 0
    if (tid < 256) {
        const float* ap = Abase + (size_t)arow * EDIM + ag * 8;
        *(uint4*)(Al[0] + a_addr(arow, ag)) = pack8(ntload4(ap), ntload4(ap + 4));
    }
    __syncthreads();

    for (int kk = 0; kk < KSTEPS; ++kk) {
        const int cur = kk & 1, nxt = cur ^ 1;

        // B fragments for this k-step straight from L2: [ks][nj], 16B per lane
        // granule index = 4*kk + 2*ks + g2 ; col offset nj*32 cols = 256 shorts
        bf16x8 bfr[2][2];
        #pragma unroll
        for (int ks = 0; ks < 2; ++ks)
            #pragma unroll
            for (int nj = 0; nj < 2; ++nj)
                bfr[ks][nj] = *(const bf16x8*)(bptr + (size_t)kk * 32768 +
                                               ks * 16384 + nj * 256);

        f32x4a a0n, a1n;
        if (kk + 1 < KSTEPS && tid < 256) {   // next A loads (NT: keep Wt in L2)
            const float* ap = Abase + (size_t)arow * EDIM + (kk + 1) * BK + ag * 8;
            a0n = ntload4(ap); a1n = ntload4(ap + 4);
        }

        // A fragments: (mi, ks) -> row mi*32 + l31, granule 2*ks + g2
        bf16x8 afr[2][2];
        #pragma unroll
        for (int mi = 0; mi < 2; ++mi)
            #pragma unroll
            for (int ks = 0; ks < 2; ++ks)
                afr[mi][ks] = *(const bf16x8*)(Al[cur] +
                                  a_addr(mi * 32 + l31, 2 * ks + g2));

        #pragma unroll
        for (int ks = 0; ks < 2; ++ks)
            #pragma unroll
            for (int mi = 0; mi < 2; ++mi)
                #pragma unroll
                for (int nj = 0; nj < 2; ++nj)
                    acc[mi][nj] = MFMA32(afr[mi][ks], bfr[ks][nj], acc[mi][nj]);

        if (kk + 1 < KSTEPS && tid < 256)
            *(uint4*)(Al[nxt] + a_addr(arow, ag)) = pack8(a0n, a1n);
        __syncthreads();
    }

    // epilogue: + dec_proj + cov*W_c -> tanh -> * v, reduce this block's 512 cols
    // C/D 32x32 layout: col = l31, row = mi*32 + (r&3) + 8*(r>>2) + 4*g2
    float dv[2], wcv[2], vvv[2];
    #pragma unroll
    for (int nj = 0; nj < 2; ++nj) {
        const int h = half * BN + wid * 64 + nj * 32 + l31;
        dv[nj]  = dp[b * HID + h];
        wcv[nj] = Wc[h];
        vvv[nj] = vv[h];
    }
    #pragma unroll
    for (int mi = 0; mi < 2; ++mi) {
        #pragma unroll
        for (int r = 0; r < 16; ++r) {
            const int row = mi * 32 + (r & 3) + 8 * (r >> 2) + 4 * g2;
            const float cv = cov_s[row];
            float x = 0.f;
            #pragma unroll
            for (int nj = 0; nj < 2; ++nj) {
                float pre = acc[mi][nj][r] + dv[nj] + cv * wcv[nj];
                float pc = fminf(pre, 20.0f);       // tanh(20)==1 in fp32
                float e2 = __expf(2.0f * pc);
                x = fmaf((e2 - 1.0f) / (e2 + 1.0f), vvv[nj], x);
            }
            x += __shfl_xor(x, 1);
            x += __shfl_xor(x, 2);
            x += __shfl_xor(x, 4);
            x += __shfl_xor(x, 8);
            x += __shfl_xor(x, 16);
            if (l31 == 0) sred[row][wid] = x;
        }
    }
    __syncthreads();
    if (tid < BM) {
        float s = 0.f;
        #pragma unroll
        for (int w = 0; w < 8; ++w) s += sred[tid][w];
        spart_out[(size_t)half * BS + b * SEQ + s0 + tid] = s;
    }
}

// ---------------- softmax + coverage_new (sums the two N-half partial scores)
__global__ void softmax_kernel(const float* __restrict__ spart,
                               const int* __restrict__ mask,
                               const float* __restrict__ cov,
                               float* __restrict__ out)
{
    __shared__ float red[8];
    int b = blockIdx.x, tid = threadIdx.x;   // 256 threads
    float vals[8];
    float mx = -1e30f;
    #pragma unroll
    for (int i = 0; i < 8; ++i) {
        int s = tid + i * 256;
        float sc = spart[b * SEQ + s] + spart[BS + b * SEQ + s];
        sc = (mask[b * SEQ + s] == 0) ? -10000.0f : sc;
        vals[i] = sc;
        mx = fmaxf(mx, sc);
    }
    for (int m = 1; m < 64; m <<= 1) mx = fmaxf(mx, __shfl_xor(mx, m));
    if ((tid & 63) == 0) red[tid >> 6] = mx;
    __syncthreads();
    mx = fmaxf(fmaxf(red[0], red[1]), fmaxf(red[2], red[3]));
    float sum = 0.f;
    #pragma unroll
    for (int i = 0; i < 8; ++i) { vals[i] = __expf(vals[i] - mx); sum += vals[i]; }
    for (int m = 1; m < 64; m <<= 1) sum += __shfl_xor(sum, m);
    if ((tid & 63) == 0) red[4 + (tid >> 6)] = sum;
    __syncthreads();
    sum = red[4] + red[5] + red[6] + red[7];
    float inv = 1.0f / sum;
    float* attn = out + BATCH * EDIM;
    float* covn = attn + BATCH * SEQ;
    #pragma unroll
    for (int i = 0; i < 8; ++i) {
        int s = tid + i * 256;
        float w = vals[i] * inv;
        attn[b * SEQ + s] = w;
        covn[b * SEQ + s] = cov[b * SEQ + s] + w;
    }
}

// ---------------- context partials: (b, e-slice, s-chunk) -> cpart
__global__ void context_partial_kernel(const float* __restrict__ enc,
                                       const float* __restrict__ attn,
                                       float* __restrict__ cpart)
{
    __shared__ float w_s[512];
    int bid = blockIdx.x;
    int sc = bid & 3;            // S-chunk of 512
    int e0 = ((bid >> 2) & 7) * 256;
    int b  = bid >> 5;
    int tid = threadIdx.x;
    w_s[tid] = attn[b * SEQ + sc * 512 + tid];
    w_s[tid + 256] = attn[b * SEQ + sc * 512 + 256 + tid];
    __syncthreads();
    const float* ep = enc + ((size_t)b * SEQ + sc * 512) * EDIM + e0 + tid;
    float acc = 0.f;
    #pragma unroll 8
    for (int s = 0; s < 512; ++s)
        acc = fmaf(w_s[s], __builtin_nontemporal_load(ep + (size_t)s * EDIM), acc);
    cpart[((size_t)sc * BATCH + b) * EDIM + e0 + tid] = acc;
}

__global__ void ctx_reduce_kernel(const float* __restrict__ cpart,
                                  float* __restrict__ ctx)
{
    int idx = blockIdx.x * 256 + threadIdx.x;     // 0 .. B*EDIM
    ctx[idx] = cpart[idx] + cpart[BATCH * EDIM + idx] +
               cpart[2 * BATCH * EDIM + idx] + cpart[3 * BATCH * EDIM + idx];
}

extern "C" void kernel_launch(void* const* d_in, const int* in_sizes, int n_in,
                              void* d_out, int out_size, void* d_ws, size_t ws_size,
                              hipStream_t stream) {
    const float* dec  = (const float*)d_in[0];
    const float* enc  = (const float*)d_in[1];
    const float* cov  = (const float*)d_in[2];
    const int*   mask = (const int*)d_in[3];
    const float* Wh   = (const float*)d_in[4];
    const float* Wd   = (const float*)d_in[5];
    const float* Wc   = (const float*)d_in[6];
    const float* v    = (const float*)d_in[7];
    float* out = (float*)d_out;

    unsigned short* Wt = (unsigned short*)d_ws;                        // 4 MiB bf16
    float* dp    = (float*)((char*)d_ws + (size_t)HID * EDIM * 2);     // 256 KiB
    float* spart = dp + BATCH * HID;                                   // 1 MiB (2 halves)
    float* cpart = spart + 2 * BS;                                     // 2 MiB

    wh_transpose_kernel<<<dim3(64 * 32), dim3(256), 0, stream>>>(Wh, Wt);
    dec_proj_kernel<<<dim3(BATCH * HID / 256), dim3(256), 0, stream>>>(dec, Wd, dp);
    scores_kernel<<<dim3((BS / BM) * 2), dim3(512), 0, stream>>>(
        enc, cov, Wt, dp, Wc, v, spart);
    softmax_kernel<<<dim3(BATCH), dim3(256), 0, stream>>>(spart, mask, cov, out);
    context_partial_kernel<<<dim3(BATCH * 8 * 4), dim3(256), 0, stream>>>(
        enc, out + BATCH * EDIM, cpart);
    ctx_reduce_kernel<<<dim3(BATCH * EDIM / 256), dim3(256), 0, stream>>>(cpart, out);
}

// Round 13
// 985.256 us; speedup vs baseline: 1.1012x; 1.1012x over previous
//
#include <hip/hip_runtime.h>
#include <hip/hip_bf16.h>
#include <stdint.h>

#define BATCH 64
#define SEQ   2048
#define HID   1024
#define EDIM  2048   // 2*HID

#define BM 64         // rows per block
#define BN 512        // cols per block (n-split = 2)
#define BK 32
#define KSTEPS (EDIM / BK)   // 64
#define BS (BATCH * SEQ)

typedef __bf16 bf16x8 __attribute__((ext_vector_type(8)));
typedef float  f32x4a __attribute__((ext_vector_type(4)));

__device__ __forceinline__ unsigned short f2bf(float x) {
    __hip_bfloat16 h = __float2bfloat16(x);
    return __builtin_bit_cast(unsigned short, h);
}

__device__ __forceinline__ uint2 pack4(f32x4a f) {
    uint2 r;
    r.x = (unsigned)f2bf(f.x) | ((unsigned)f2bf(f.y) << 16);
    r.y = (unsigned)f2bf(f.z) | ((unsigned)f2bf(f.w) << 16);
    return r;
}

__device__ __forceinline__ f32x4a ntload4(const float* p) {
    return __builtin_nontemporal_load((const f32x4a*)p);
}

// A-tile LDS addrs (verified in R11-V1): write 8B chunks, read 16B granules
__device__ __forceinline__ int a_waddr(int row, int c) {
    return (row << 6) + ((c ^ (row & 6)) << 3);
}
__device__ __forceinline__ int a_raddr(int row, int g) {
    return (row << 6) + ((g ^ ((row >> 1) & 3)) << 4);
}

// ---------------- prep: W_h (EDIM x HID fp32) -> Wt bf16 granule-major:
// element (h,e) at Wt[(e>>3)*8192 + h*8 + (e&7)]  (fragment = contiguous 16B)
__global__ void wh_transpose_kernel(const float* __restrict__ Wh,
                                    unsigned short* __restrict__ Wt) {
    __shared__ float tile[32][33];
    int bx = blockIdx.x & 63;    // e-tile
    int by = blockIdx.x >> 6;    // h-tile
    int e0 = bx * 32, h0 = by * 32;
    int tx = threadIdx.x & 31, ty = threadIdx.x >> 5;   // 32 x 8
    #pragma unroll
    for (int i = 0; i < 4; ++i)
        tile[ty + 8 * i][tx] = Wh[(size_t)(e0 + ty + 8 * i) * HID + h0 + tx];
    __syncthreads();
    if (ty < 4) {
        uint4 wv;
        unsigned short* ws = (unsigned short*)&wv;
        #pragma unroll
        for (int j = 0; j < 8; ++j) ws[j] = f2bf(tile[ty * 8 + j][tx]);
        *(uint4*)&Wt[(size_t)((e0 >> 3) + ty) * 8192 + (size_t)(h0 + tx) * 8] = wv;
    }
}

// ---------------- prep: dec_proj = decoder_hidden @ W_d  (fp32, (B,HID))
__global__ void dec_proj_kernel(const float* __restrict__ dec,
                                const float* __restrict__ Wd,
                                float* __restrict__ dp) {
    int gid = blockIdx.x * 256 + threadIdx.x;
    int b = gid >> 10, h = gid & 1023;
    const float* dr = dec + b * HID;
    float acc = 0.f;
    #pragma unroll 4
    for (int k = 0; k < HID; ++k) acc = fmaf(dr[k], Wd[(size_t)k * HID + h], acc);
    dp[gid] = acc;
}

#define MFMA16(a, bfv, c) __builtin_amdgcn_mfma_f32_16x16x32_bf16(a, bfv, c, 0, 0, 0)

// One pipelined k-step: consume BCUR, prefetch BNXT (loads cross the raw barrier)
#define KSTEP(kk, BCUR, BNXT, CURBUF, NXTBUF)                                   \
  {                                                                             \
    if ((kk) + 1 < KSTEPS) {                                                    \
      const unsigned short* bs = bptr + (size_t)((kk) + 1) * 32768;             \
      _Pragma("unroll")                                                         \
      for (int nj = 0; nj < 4; ++nj)                                            \
        BNXT[nj] = *(const bf16x8*)(bs + nj * 128);                             \
    }                                                                           \
    __builtin_amdgcn_s_setprio(1);                                              \
    _Pragma("unroll")                                                           \
    for (int mi = 0; mi < 4; ++mi) {                                            \
      bf16x8 afr = *(const bf16x8*)(CURBUF + a_raddr(mi * 16 + c15, g4));       \
      _Pragma("unroll")                                                         \
      for (int nj = 0; nj < 4; ++nj)                                            \
        acc[mi][nj] = MFMA16(afr, BCUR[nj], acc[mi][nj]);                       \
    }                                                                           \
    __builtin_amdgcn_s_setprio(0);                                              \
    if ((kk) + 1 < KSTEPS) *(uint2*)(NXTBUF + wb) = pack4(aL);                  \
    if ((kk) + 2 < KSTEPS) aL = ntload4(ap0 + ((kk) + 2) * BK);                 \
    asm volatile("s_waitcnt lgkmcnt(0)" ::: "memory");                          \
    __builtin_amdgcn_s_barrier();                                               \
    __builtin_amdgcn_sched_barrier(0);                                          \
  }

// ---------------- main fused scores kernel: 64 rows x 512 cols, 8 waves,
// raw-barrier pipeline: B(k+1) regs + A(k+2) reg in flight ACROSS the barrier
// (no vmcnt(0) drain). 2 blocks/CU.
__global__ __launch_bounds__(512, 4) void scores_kernel(
    const float* __restrict__ enc, const float* __restrict__ cov,
    const unsigned short* __restrict__ Wt, const float* __restrict__ dp,
    const float* __restrict__ Wc, const float* __restrict__ vv,
    float* __restrict__ spart_out)
{
    __shared__ char Al[2][4096];       // A dbuf: 64 rows x 64B, swizzled
    __shared__ float cov_s[BM];
    __shared__ float sred[BM][8];

    const int tid  = threadIdx.x;
    const int lane = tid & 63;
    const int wid  = tid >> 6;       // 0..7 : 64-col slice
    const int c15  = lane & 15;
    const int g4   = lane >> 4;      // 0..3 : k-granule

    // bid pairs: (m, half=0/1) adjacent -> enc panel L3-hot on 2nd read
    const int bid  = blockIdx.x;
    const int half = bid & 1;
    const int m    = bid >> 1;                 // 0..2047
    const int b    = m >> 5;
    const int s0   = (m & 31) * BM;

    const float* Abase = enc + (size_t)(b * SEQ + s0) * EDIM;
    // A staging: ALL 512 threads, one f32x4 (16B fp32 -> 8B bf16) per k-step
    const int arow = tid >> 3;                 // 0..63
    const int ac   = tid & 7;                  // chunk of 4 floats
    const float* ap0 = Abase + (size_t)arow * EDIM + ac * 4;
    const int wb = a_waddr(arow, ac);

    // per-lane B base: granule g4, col h = half*512 + wid*64 + c15 (+16*nj)
    const unsigned short* bptr =
        Wt + (size_t)g4 * 8192 + (size_t)(half * BN + wid * 64 + c15) * 8;

    f32x4a acc[4][4];
    #pragma unroll
    for (int mi = 0; mi < 4; ++mi)
        #pragma unroll
        for (int nj = 0; nj < 4; ++nj)
            #pragma unroll
            for (int r = 0; r < 4; ++r) acc[mi][nj][r] = 0.f;

    if (tid < BM) cov_s[tid] = cov[b * SEQ + s0 + tid];

    // prologue: A(0)->LDS buf0, B(0)->bA, A(1)->reg
    bf16x8 bA[4], bB[4];
    f32x4a aL = ntload4(ap0);
    #pragma unroll
    for (int nj = 0; nj < 4; ++nj)
        bA[nj] = *(const bf16x8*)(bptr + nj * 128);
    *(uint2*)(Al[0] + wb) = pack4(aL);
    aL = ntload4(ap0 + BK);
    asm volatile("s_waitcnt lgkmcnt(0)" ::: "memory");
    __builtin_amdgcn_s_barrier();
    __builtin_amdgcn_sched_barrier(0);

    for (int kk2 = 0; kk2 < KSTEPS; kk2 += 2) {
        KSTEP(kk2,     bA, bB, Al[0], Al[1]);
        KSTEP(kk2 + 1, bB, bA, Al[1], Al[0]);
    }

    // epilogue: + dec_proj + cov*W_c -> tanh -> * v, reduce this block's 512 cols
    float spart[4][4];
    #pragma unroll
    for (int mi = 0; mi < 4; ++mi)
        #pragma unroll
        for (int r = 0; r < 4; ++r) spart[mi][r] = 0.f;

    #pragma unroll
    for (int nj = 0; nj < 4; ++nj) {
        const int h = half * BN + wid * 64 + nj * 16 + c15;
        const float dv  = dp[b * HID + h];
        const float wcv = Wc[h];
        const float vvv = vv[h];
        #pragma unroll
        for (int mi = 0; mi < 4; ++mi) {
            #pragma unroll
            for (int r = 0; r < 4; ++r) {
                const int row = mi * 16 + g4 * 4 + r;
                float pre = acc[mi][nj][r] + dv + cov_s[row] * wcv;
                float pc = fminf(pre, 20.0f);       // tanh(20)==1 in fp32
                float e2 = __expf(2.0f * pc);
                spart[mi][r] = fmaf((e2 - 1.0f) / (e2 + 1.0f), vvv, spart[mi][r]);
            }
        }
    }
    #pragma unroll
    for (int mi = 0; mi < 4; ++mi) {
        #pragma unroll
        for (int r = 0; r < 4; ++r) {
            float x = spart[mi][r];
            x += __shfl_xor(x, 1);
            x += __shfl_xor(x, 2);
            x += __shfl_xor(x, 4);
            x += __shfl_xor(x, 8);
            if (c15 == 0) sred[mi * 16 + g4 * 4 + r][wid] = x;
        }
    }
    __syncthreads();
    if (tid < BM) {
        float s = 0.f;
        #pragma unroll
        for (int w = 0; w < 8; ++w) s += sred[tid][w];
        spart_out[(size_t)half * BS + b * SEQ + s0 + tid] = s;
    }
}

// ---------------- softmax + coverage_new (sums the two N-half partial scores)
__global__ void softmax_kernel(const float* __restrict__ spart,
                               const int* __restrict__ mask,
                               const float* __restrict__ cov,
                               float* __restrict__ out)
{
    __shared__ float red[8];
    int b = blockIdx.x, tid = threadIdx.x;   // 256 threads
    float vals[8];
    float mx = -1e30f;
    #pragma unroll
    for (int i = 0; i < 8; ++i) {
        int s = tid + i * 256;
        float sc = spart[b * SEQ + s] + spart[BS + b * SEQ + s];
        sc = (mask[b * SEQ + s] == 0) ? -10000.0f : sc;
        vals[i] = sc;
        mx = fmaxf(mx, sc);
    }
    for (int m = 1; m < 64; m <<= 1) mx = fmaxf(mx, __shfl_xor(mx, m));
    if ((tid & 63) == 0) red[tid >> 6] = mx;
    __syncthreads();
    mx = fmaxf(fmaxf(red[0], red[1]), fmaxf(red[2], red[3]));
    float sum = 0.f;
    #pragma unroll
    for (int i = 0; i < 8; ++i) { vals[i] = __expf(vals[i] - mx); sum += vals[i]; }
    for (int m = 1; m < 64; m <<= 1) sum += __shfl_xor(sum, m);
    if ((tid & 63) == 0) red[4 + (tid >> 6)] = sum;
    __syncthreads();
    sum = red[4] + red[5] + red[6] + red[7];
    float inv = 1.0f / sum;
    float* attn = out + BATCH * EDIM;
    float* covn = attn + BATCH * SEQ;
    #pragma unroll
    for (int i = 0; i < 8; ++i) {
        int s = tid + i * 256;
        float w = vals[i] * inv;
        attn[b * SEQ + s] = w;
        covn[b * SEQ + s] = cov[b * SEQ + s] + w;
    }
}

// ---------------- context partials: (b, e-slice, s-chunk) -> cpart
__global__ void context_partial_kernel(const float* __restrict__ enc,
                                       const float* __restrict__ attn,
                                       float* __restrict__ cpart)
{
    __shared__ float w_s[512];
    int bid = blockIdx.x;
    int sc = bid & 3;            // S-chunk of 512
    int e0 = ((bid >> 2) & 7) * 256;
    int b  = bid >> 5;
    int tid = threadIdx.x;
    w_s[tid] = attn[b * SEQ + sc * 512 + tid];
    w_s[tid + 256] = attn[b * SEQ + sc * 512 + 256 + tid];
    __syncthreads();
    const float* ep = enc + ((size_t)b * SEQ + sc * 512) * EDIM + e0 + tid;
    float acc = 0.f;
    #pragma unroll 8
    for (int s = 0; s < 512; ++s)
        acc = fmaf(w_s[s], __builtin_nontemporal_load(ep + (size_t)s * EDIM), acc);
    cpart[((size_t)sc * BATCH + b) * EDIM + e0 + tid] = acc;
}

__global__ void ctx_reduce_kernel(const float* __restrict__ cpart,
                                  float* __restrict__ ctx)
{
    int idx = blockIdx.x * 256 + threadIdx.x;     // 0 .. B*EDIM
    ctx[idx] = cpart[idx] + cpart[BATCH * EDIM + idx] +
               cpart[2 * BATCH * EDIM + idx] + cpart[3 * BATCH * EDIM + idx];
}

extern "C" void kernel_launch(void* const* d_in, const int* in_sizes, int n_in,
                              void* d_out, int out_size, void* d_ws, size_t ws_size,
                              hipStream_t stream) {
    const float* dec  = (const float*)d_in[0];
    const float* enc  = (const float*)d_in[1];
    const float* cov  = (const float*)d_in[2];
    const int*   mask = (const int*)d_in[3];
    const float* Wh   = (const float*)d_in[4];
    const float* Wd   = (const float*)d_in[5];
    const float* Wc   = (const float*)d_in[6];
    const float* v    = (const float*)d_in[7];
    float* out = (float*)d_out;

    unsigned short* Wt = (unsigned short*)d_ws;                        // 4 MiB bf16
    float* dp    = (float*)((char*)d_ws + (size_t)HID * EDIM * 2);     // 256 KiB
    float* spart = dp + BATCH * HID;                                   // 1 MiB (2 halves)
    float* cpart = spart + 2 * BS;                                     // 2 MiB

    wh_transpose_kernel<<<dim3(64 * 32), dim3(256), 0, stream>>>(Wh, Wt);
    dec_proj_kernel<<<dim3(BATCH * HID / 256), dim3(256), 0, stream>>>(dec, Wd, dp);
    scores_kernel<<<dim3((BS / BM) * 2), dim3(512), 0, stream>>>(
        enc, cov, Wt, dp, Wc, v, spart);
    softmax_kernel<<<dim3(BATCH), dim3(256), 0, stream>>>(spart, mask, cov, out);
    context_partial_kernel<<<dim3(BATCH * 8 * 4), dim3(256), 0, stream>>>(
        enc, out + BATCH * EDIM, cpart);
    ctx_reduce_kernel<<<dim3(BATCH * EDIM / 256), dim3(256), 0, stream>>>(cpart, out);
}